// Round 6
// baseline (119.495 us; speedup 1.0000x reference)
//
#include <hip/hip_runtime.h>
#include <hip/hip_bf16.h>

#define BATCH 65536
#define DIN   128
#define DH    512
#define DOUT  128
#define ROWS  32

typedef __attribute__((ext_vector_type(4))) float f32x4;
typedef __attribute__((ext_vector_type(8))) short s16x8;

__device__ __forceinline__ ushort f32_to_bf16_rn(float f) {
    uint32_t u = __float_as_uint(f);
    uint32_t r = (u + 0x7FFFu + ((u >> 16) & 1u)) >> 16;
    return (ushort)r;
}
__device__ __forceinline__ float bf16_to_f32(ushort h) {
    return __uint_as_float(((uint32_t)h) << 16);
}

__device__ __forceinline__ f32x4 mfma16(s16x8 a, s16x8 b, f32x4 c) {
    return __builtin_amdgcn_mfma_f32_16x16x32_bf16(a, b, c, 0, 0, 0);
}

struct Split8 { s16x8 h, l; };
__device__ __forceinline__ Split8 split8(f32x4 v0, f32x4 v1) {
    Split8 s;
#pragma unroll
    for (int j = 0; j < 4; ++j) {
        ushort hh = f32_to_bf16_rn(v0[j]);
        s.h[j] = (short)hh;
        s.l[j] = (short)f32_to_bf16_rn(v0[j] - bf16_to_f32(hh));
    }
#pragma unroll
    for (int j = 0; j < 4; ++j) {
        ushort hh = f32_to_bf16_rn(v1[j]);
        s.h[4 + j] = (short)hh;
        s.l[4 + j] = (short)f32_to_bf16_rn(v1[j] - bf16_to_f32(hh));
    }
    return s;
}

// ---------------------------------------------------------------------------
// prep: unchanged (verified 3x). decay = softmax(a); B,C split to bf16 hi/lo
// fragment-linear: perm[(f*64+lane)*8+j] = M[k][col],
// k = ks*32 + (lane>>4)*8 + j, col = cg*16 + (lane&15).
// B: f = cg*4 + ks (cg 0..31); C: f = cg*16 + ksg (cg 0..7, ksg 0..15).
// ---------------------------------------------------------------------------
__global__ void prep_kernel(const float* __restrict__ a,
                            const float* __restrict__ b,
                            const float* __restrict__ c,
                            float* __restrict__ decay,
                            ushort* __restrict__ bhi, ushort* __restrict__ blo,
                            ushort* __restrict__ chi, ushort* __restrict__ clo)
{
    const int t = threadIdx.x;
    if (blockIdx.x == 0) {
        __shared__ float red[256];
        float v0 = a[t], v1 = a[t + 256];
        red[t] = fmaxf(v0, v1);
        __syncthreads();
        for (int s = 128; s > 0; s >>= 1) {
            if (t < s) red[t] = fmaxf(red[t], red[t + s]);
            __syncthreads();
        }
        float M = red[0];
        __syncthreads();
        float e0 = expf(v0 - M), e1 = expf(v1 - M);
        red[t] = e0 + e1;
        __syncthreads();
        for (int s = 128; s > 0; s >>= 1) {
            if (t < s) red[t] += red[t + s];
            __syncthreads();
        }
        float S = red[0];
        decay[t]       = e0 / S;
        decay[t + 256] = e1 / S;
    } else {
        const int p = (blockIdx.x - 1) * 256 + t;
        const int mtx = p >> 13;
        const int q = p & 8191;
        const int f = q >> 6;
        const int l = q & 63;
        s16x8 hi, lo;
        if (mtx == 0) {
            const int cg = f >> 2, ks = f & 3;
            const int col = cg * 16 + (l & 15);
            const int kbase = ks * 32 + (l >> 4) * 8;
#pragma unroll
            for (int j = 0; j < 8; ++j) {
                float v = b[(size_t)(kbase + j) * DH + col];
                ushort h = f32_to_bf16_rn(v);
                hi[j] = (short)h;
                lo[j] = (short)f32_to_bf16_rn(v - bf16_to_f32(h));
            }
            *(s16x8*)(bhi + (size_t)q * 8) = hi;
            *(s16x8*)(blo + (size_t)q * 8) = lo;
        } else {
            const int cg = f >> 4, ks = f & 15;
            const int col = cg * 16 + (l & 15);
            const int kbase = ks * 32 + (l >> 4) * 8;
#pragma unroll
            for (int j = 0; j < 8; ++j) {
                float v = c[(size_t)(kbase + j) * DOUT + col];
                ushort h = f32_to_bf16_rn(v);
                hi[j] = (short)h;
                lo[j] = (short)f32_to_bf16_rn(v - bf16_to_f32(h));
            }
            *(s16x8*)(chi + (size_t)q * 8) = hi;
            *(s16x8*)(clo + (size_t)q * 8) = lo;
        }
    }
}

// ---------------------------------------------------------------------------
// fused v2: block = 32 rows, chunk = 128 cols (4 chunks). 4 waves. LDS 32KB
// (A 16KB + X 16KB) -> 5 blocks/CU target. Per chunk:
//   GEMM1: wave wc cols [ct*128+wc*32, +32) (2 nf), K=128 -> 48 MFMA.
//   epilogue: v = acc1 + decay*x (x prefetched 16 dwords before GEMM1);
//             store xn; split v into X LDS ([32][128], same layout as A).
//   GEMM2: out[32x128] += X @ C-chunk, K=128 -> 48 MFMA. acc2 persists.
// Barriers: 2/chunk (+1 initial) = 9 vs 17 before.
// ---------------------------------------------------------------------------
__global__ __launch_bounds__(256, 4)
void rnn_fused(const float* __restrict__ u, const float* __restrict__ x,
               const float* __restrict__ decay,
               const ushort* __restrict__ bhi, const ushort* __restrict__ blo,
               const ushort* __restrict__ chi, const ushort* __restrict__ clo,
               float* __restrict__ xn, float* __restrict__ out)
{
    __shared__ __align__(16) char smem[32768];
    ushort* Ah = (ushort*)smem;             // [32][128] bf16 hi, swz, 8KB
    ushort* Al = (ushort*)(smem + 8192);
    ushort* Xh = (ushort*)(smem + 16384);   // [32][128] bf16 hi, swz, 8KB
    ushort* Xl = (ushort*)(smem + 24576);

    const int t = threadIdx.x;
    const int lane = t & 63, wc = t >> 6;
    const int cl = lane & 15, hk = lane >> 4;
    const int row0 = blockIdx.x * ROWS;

    {   // stage A: u[32][128] f32 -> hi/lo bf16 swizzled; 64B/thread coalesced
        const int r = t >> 3;
        const int kb = (t & 7) * 2;
#pragma unroll
        for (int i = 0; i < 2; ++i) {
            const float* src = u + (size_t)(row0 + r) * DIN + (kb + i) * 8;
            f32x4 v0 = *(const f32x4*)src;
            f32x4 v1 = *(const f32x4*)(src + 4);
            Split8 s = split8(v0, v1);
            const int byte = (r * 256 + (kb + i) * 16) ^ ((r & 7) << 4);
            *(s16x8*)((char*)Ah + byte) = s.h;
            *(s16x8*)((char*)Al + byte) = s.l;
        }
    }
    __syncthreads();

    f32x4 acc2[2][2];
#pragma unroll
    for (int mf = 0; mf < 2; ++mf)
#pragma unroll
        for (int nf = 0; nf < 2; ++nf)
            acc2[mf][nf] = (f32x4){0.f, 0.f, 0.f, 0.f};

    for (int ct = 0; ct < 4; ++ct) {
        // ---- prefetch x + decay for this chunk (hides under GEMM1)
        float dv[2], xv[2][2][4];
#pragma unroll
        for (int nf = 0; nf < 2; ++nf) {
            const int col = ct * 128 + wc * 32 + nf * 16 + cl;
            dv[nf] = decay[col];
#pragma unroll
            for (int mf = 0; mf < 2; ++mf)
#pragma unroll
                for (int j = 0; j < 4; ++j)
                    xv[nf][mf][j] = x[(size_t)(row0 + mf * 16 + hk * 4 + j) * DH + col];
        }

        // ---- GEMM1: acc1 = u @ B chunk; wave tile 32 rows x 32 cols, K=128
        f32x4 acc1[2][2];
#pragma unroll
        for (int mf = 0; mf < 2; ++mf)
#pragma unroll
            for (int nf = 0; nf < 2; ++nf)
                acc1[mf][nf] = (f32x4){0.f, 0.f, 0.f, 0.f};
#pragma unroll
        for (int ks = 0; ks < 4; ++ks) {
            const int ko = ks * 32 + hk * 8;
            s16x8 ah[2], al[2];
#pragma unroll
            for (int mf = 0; mf < 2; ++mf) {
                const int r = mf * 16 + cl;
                const int byte = (r * 256 + ko * 2) ^ ((r & 7) << 4);
                ah[mf] = *(const s16x8*)((const char*)Ah + byte);
                al[mf] = *(const s16x8*)((const char*)Al + byte);
            }
#pragma unroll
            for (int nf = 0; nf < 2; ++nf) {
                const size_t fB = (size_t)((ct * 8 + wc * 2 + nf) * 4 + ks) * 512 + lane * 8;
                s16x8 bh = *(const s16x8*)(bhi + fB);
                s16x8 bl = *(const s16x8*)(blo + fB);
#pragma unroll
                for (int mf = 0; mf < 2; ++mf) acc1[mf][nf] = mfma16(ah[mf], bh, acc1[mf][nf]);
#pragma unroll
                for (int mf = 0; mf < 2; ++mf) acc1[mf][nf] = mfma16(ah[mf], bl, acc1[mf][nf]);
#pragma unroll
                for (int mf = 0; mf < 2; ++mf) acc1[mf][nf] = mfma16(al[mf], bh, acc1[mf][nf]);
            }
        }

        __syncthreads();   // prev chunk's GEMM2 X-reads complete (WAR)

        // ---- epilogue: xn = acc1 + decay*x; split into X LDS
#pragma unroll
        for (int nf = 0; nf < 2; ++nf) {
            const int col = ct * 128 + wc * 32 + nf * 16 + cl;
            const int colB = wc * 32 + nf * 16 + cl;
#pragma unroll
            for (int mf = 0; mf < 2; ++mf) {
#pragma unroll
                for (int j = 0; j < 4; ++j) {
                    const int rl = mf * 16 + hk * 4 + j;
                    const float v = acc1[mf][nf][j] + dv[nf] * xv[nf][mf][j];
                    xn[(size_t)(row0 + rl) * DH + col] = v;
                    const ushort hh = f32_to_bf16_rn(v);
                    const ushort ll = f32_to_bf16_rn(v - bf16_to_f32(hh));
                    const int cbyte = (rl * 256 + colB * 2) ^ ((rl & 7) << 4);
                    *(ushort*)((char*)Xh + cbyte) = hh;
                    *(ushort*)((char*)Xl + cbyte) = ll;
                }
            }
        }
        __syncthreads();   // X visible to all waves

        // ---- GEMM2: out += X @ C-chunk; wave tile 32 rows x 32 cols, K=128
#pragma unroll
        for (int ks2 = 0; ks2 < 4; ++ks2) {
            const int ko = ks2 * 32 + hk * 8;
            s16x8 ah2[2], al2[2];
#pragma unroll
            for (int mf = 0; mf < 2; ++mf) {
                const int r = mf * 16 + cl;
                const int byte = (r * 256 + ko * 2) ^ ((r & 7) << 4);
                ah2[mf] = *(const s16x8*)((const char*)Xh + byte);
                al2[mf] = *(const s16x8*)((const char*)Xl + byte);
            }
#pragma unroll
            for (int nf = 0; nf < 2; ++nf) {
                const size_t fC = (size_t)((wc * 2 + nf) * 16 + ct * 4 + ks2) * 512 + lane * 8;
                s16x8 ch = *(const s16x8*)(chi + fC);
                s16x8 cc = *(const s16x8*)(clo + fC);
#pragma unroll
                for (int mf = 0; mf < 2; ++mf) acc2[mf][nf] = mfma16(ah2[mf], ch, acc2[mf][nf]);
#pragma unroll
                for (int mf = 0; mf < 2; ++mf) acc2[mf][nf] = mfma16(ah2[mf], cc, acc2[mf][nf]);
#pragma unroll
                for (int mf = 0; mf < 2; ++mf) acc2[mf][nf] = mfma16(al2[mf], ch, acc2[mf][nf]);
            }
        }
    }

    // ---- final: store out[32 x 128]; wave covers cols [wc*32, +32)
#pragma unroll
    for (int nf = 0; nf < 2; ++nf) {
        const int ocol = wc * 32 + nf * 16 + cl;
#pragma unroll
        for (int mf = 0; mf < 2; ++mf) {
#pragma unroll
            for (int j = 0; j < 4; ++j) {
                const int rl = mf * 16 + hk * 4 + j;
                out[(size_t)(row0 + rl) * DOUT + ocol] = acc2[mf][nf][j];
            }
        }
    }
}

extern "C" void kernel_launch(void* const* d_in, const int* in_sizes, int n_in,
                              void* d_out, int out_size, void* d_ws, size_t ws_size,
                              hipStream_t stream)
{
    const float* x = (const float*)d_in[0];
    const float* u = (const float*)d_in[1];
    const float* a = (const float*)d_in[2];
    const float* b = (const float*)d_in[3];
    const float* c = (const float*)d_in[4];

    float* xn  = (float*)d_out;                       // [BATCH][DH]
    float* out = xn + (size_t)BATCH * DH;             // [BATCH][DOUT]

    float*  decay = (float*)d_ws;                     // 512 f32
    ushort* bhi = (ushort*)((char*)d_ws + 4096);      // 4 x 128KB perm-split mats
    ushort* blo = bhi + 128 * 512;
    ushort* chi = blo + 128 * 512;
    ushort* clo = chi + 512 * 128;

    prep_kernel<<<dim3(65), dim3(256), 0, stream>>>(a, b, c, decay, bhi, blo, chi, clo);
    rnn_fused<<<dim3(BATCH / ROWS), dim3(256), 0, stream>>>(u, x, decay, bhi, blo, chi, clo, xn, out);
}